// Round 3
// baseline (766.594 us; speedup 1.0000x reference)
//
#include <hip/hip_runtime.h>
#include <math.h>

#define B_SZ 1024
#define IN_SZ 2048
#define H0_SZ 4096
#define H1_SZ 4096
#define OUT_SZ 1000

typedef _Float16 f16;
typedef __attribute__((ext_vector_type(4))) _Float16 f16x4;
typedef __attribute__((ext_vector_type(8))) _Float16 f16x8;
typedef __attribute__((ext_vector_type(4))) float f32x4;

// ---------------- ws layout (bytes) ----------------
// doubles acc[8]: 0=xz 1=sum_ls 2=sum_eps2 3=flowz 4=sum_mu2 5=sum_expls 6=ce_sum
#define OFF_N0     64ULL
#define OFF_N1     68ULL
#define OFF_MSUM0  256ULL
#define OFF_MSUM1  4352ULL
#define OFF_CPOS0  8448ULL
#define OFF_CPOS1  24832ULL
#define OFF_IDX0   41216ULL
#define OFF_IDX1   57600ULL
#define OFF_BS0    73984ULL
#define OFF_BS1    90368ULL
#define OFF_BSO    106752ULL
#define OFF_XH     131072ULL
#define OFF_XL     4325376ULL
#define OFF_H0H    8519680ULL
#define OFF_H0L    16908288ULL
#define OFF_H1H    25296896ULL
#define OFF_H1L    33685504ULL
#define OFF_W0CH   42074112ULL
#define OFF_W0CL   58851328ULL
#define OFF_W1CH   75628544ULL
#define OFF_W1CL   109182976ULL
#define OFF_WOCH   142737408ULL
#define OFF_WOCL   150929408ULL
#define OFF_PART   159121408ULL

__device__ __forceinline__ void gload_lds16(const void* g, void* l)
{
    __builtin_amdgcn_global_load_lds((const __attribute__((address_space(1))) void*)g,
                                     (__attribute__((address_space(3))) void*)l, 16, 0, 0);
}

__device__ __forceinline__ void reduce4_atomic(double v0, double v1, double v2, double v3,
                                               double* d0, double* d1, double* d2, double* d3)
{
    __shared__ double sh[4][4];
    double v[4] = {v0, v1, v2, v3};
    int lane = threadIdx.x & 63, wid = threadIdx.x >> 6;
#pragma unroll
    for (int a = 0; a < 4; ++a) {
        double x = v[a];
#pragma unroll
        for (int o = 32; o > 0; o >>= 1) x += __shfl_down(x, o, 64);
        if (lane == 0) sh[a][wid] = x;
    }
    __syncthreads();
    if (threadIdx.x == 0) {
        double t0 = sh[0][0] + sh[0][1] + sh[0][2] + sh[0][3];
        double t1 = sh[1][0] + sh[1][1] + sh[1][2] + sh[1][3];
        double t2 = sh[2][0] + sh[2][1] + sh[2][2] + sh[2][3];
        double t3 = sh[3][0] + sh[3][1] + sh[3][2] + sh[3][3];
        if (d0) atomicAdd(d0, t0);
        if (d1) atomicAdd(d1, t1);
        if (d2) atomicAdd(d2, t2);
        if (d3) atomicAdd(d3, t3);
    }
}

// ---- build compaction maps: cpos (exclusive prefix), idx (compact->orig), n
__global__ __launch_bounds__(1024) void idxbuild_kernel(
    const int* __restrict__ mask0, const int* __restrict__ mask1,
    int* __restrict__ cpos0, int* __restrict__ idx0, int* __restrict__ n0,
    int* __restrict__ cpos1, int* __restrict__ idx1, int* __restrict__ n1)
{
    __shared__ int sh[1024];
    const int t = threadIdx.x;
    for (int pass = 0; pass < 2; ++pass) {
        const int* mask = pass ? mask1 : mask0;
        int* cpos = pass ? cpos1 : cpos0;
        int* idx = pass ? idx1 : idx0;
        int* np = pass ? n1 : n0;
        int4 m = ((const int4*)mask)[t];
        int s = m.x + m.y + m.z + m.w;
        sh[t] = s;
        __syncthreads();
        for (int o = 1; o < 1024; o <<= 1) {
            int v = (t >= o) ? sh[t - o] : 0;
            __syncthreads();
            sh[t] += v;
            __syncthreads();
        }
        int run = sh[t] - s;
        int4 cp;
        cp.x = run; cp.y = run + m.x; cp.z = cp.y + m.y; cp.w = cp.z + m.z;
        ((int4*)cpos)[t] = cp;
        if (m.x) idx0[0] = idx0[0];  // no-op placeholder removed below
        if (m.x) idx[cp.x] = 4 * t + 0;
        if (m.y) idx[cp.y] = 4 * t + 1;
        if (m.z) idx[cp.z] = 4 * t + 2;
        if (m.w) idx[cp.w] = 4 * t + 3;
        if (t == 1023) *np = sh[1023];
        __syncthreads();
    }
}

// ---- split x into f16 hi/lo planes, fused with (x @ z_w).sum()
__global__ __launch_bounds__(256) void splitx_kernel(const float4* __restrict__ x,
                                                     const float4* __restrict__ zw,
                                                     f16x4* __restrict__ xh, f16x4* __restrict__ xl,
                                                     double* acc)
{
    const int n4 = B_SZ * IN_SZ / 4;
    double s = 0;
    int i = blockIdx.x * blockDim.x + threadIdx.x;
    int stride = gridDim.x * blockDim.x;
    for (; i < n4; i += stride) {
        float4 v = x[i];
        float4 z = zw[i & (IN_SZ / 4 - 1)];
        s += (double)v.x * z.x + (double)v.y * z.y + (double)v.z * z.z + (double)v.w * z.w;
        f16 h0 = (f16)v.x, h1 = (f16)v.y, h2 = (f16)v.z, h3 = (f16)v.w;
        f16x4 hv = {h0, h1, h2, h3};
        f16x4 lv = {(f16)(v.x - (float)h0), (f16)(v.y - (float)h1),
                    (f16)(v.z - (float)h2), (f16)(v.w - (float)h3)};
        xh[i] = hv; xl[i] = lv;
    }
    reduce4_atomic(s, 0.0, 0.0, 0.0, acc + 0, nullptr, nullptr, nullptr);
}

// ---- fused GFN flow + per-row mask sum (one block per batch row)
__global__ __launch_bounds__(256) void flowmsum_kernel(const int* __restrict__ mz,
                                                       const float* __restrict__ pfz,
                                                       const int* __restrict__ maskmu,
                                                       float* __restrict__ msum, double* acc)
{
    const int b = blockIdx.x;
    const int4* m4 = (const int4*)(mz + (size_t)b * 4096);
    const float4* p4 = (const float4*)(pfz + (size_t)b * 4096);
    const int4* k4 = (const int4*)maskmu;
    int s = 0;
    double fl = 0;
    for (int i = threadIdx.x; i < 1024; i += 256) {
        int4 m = m4[i];
        float4 p = p4[i];
        int4 k = k4[i];
        s += m.x * k.x + m.y * k.y + m.z * k.z + m.w * k.w;
        float a0 = fminf(fmaxf(p.x, 1e-6f), 1.0f - 1e-6f);
        float a1 = fminf(fmaxf(p.y, 1e-6f), 1.0f - 1e-6f);
        float a2 = fminf(fmaxf(p.z, 1e-6f), 1.0f - 1e-6f);
        float a3 = fminf(fmaxf(p.w, 1e-6f), 1.0f - 1e-6f);
        fl += (double)logf(m.x ? a0 : 1.0f - a0);
        fl += (double)logf(m.y ? a1 : 1.0f - a1);
        fl += (double)logf(m.z ? a2 : 1.0f - a2);
        fl += (double)logf(m.w ? a3 : 1.0f - a3);
    }
#pragma unroll
    for (int o = 32; o > 0; o >>= 1) {
        s += __shfl_down(s, o, 64);
        fl += __shfl_down(fl, o, 64);
    }
    __shared__ int shi[4];
    __shared__ double shd[4];
    if ((threadIdx.x & 63) == 0) { shi[threadIdx.x >> 6] = s; shd[threadIdx.x >> 6] = fl; }
    __syncthreads();
    if (threadIdx.x == 0) {
        msum[b] = (float)(shi[0] + shi[1] + shi[2] + shi[3]);
        atomicAdd(acc + 3, shd[0] + shd[1] + shd[2] + shd[3]);
    }
}

// ---- sample biases (+ optional flow reductions)
template <int RED>
__global__ __launch_bounds__(256) void bsample_kernel(const float* __restrict__ bmu,
                                                      const float* __restrict__ bls,
                                                      const float* __restrict__ beps,
                                                      float* __restrict__ out, int n, double* acc)
{
    int i = blockIdx.x * 256 + threadIdx.x;
    float l = 0.f, e = 0.f;
    if (i < n) {
        l = bls[i]; e = beps[i];
        out[i] = fmaf(__expf(l), e, bmu[i]);
    }
    if (RED) {
        double sls = (i < n) ? (double)l : 0.0;
        double se2 = (i < n) ? (double)e * e : 0.0;
        reduce4_atomic(sls, se2, 0.0, 0.0, acc + 1, acc + 2, nullptr, nullptr);
    }
}

// ---- sample W into compacted split-f16 planes; one block per source row.
// ROWC: row-compact via maskR/cposR. COLC: column-scatter via maskC/cposC.
// RED: accumulate flow/decay reductions (over ALL elements, even dropped ones).
template <int COLS, int ROWC, int COLC, int RED>
__global__ __launch_bounds__(256) void wsample_kernel(
    const float* __restrict__ mu, const float* __restrict__ ls, const float* __restrict__ eps,
    const int* __restrict__ maskR, const int* __restrict__ cposR,
    const int* __restrict__ maskC, const int* __restrict__ cposC,
    f16* __restrict__ hi, f16* __restrict__ lo, int DSTS, double* acc)
{
    const int r = blockIdx.x;
    const size_t rb = (size_t)r * COLS;
    const float4* m4 = (const float4*)(mu + rb);
    const float4* l4 = (const float4*)(ls + rb);
    const float4* e4 = (const float4*)(eps + rb);
    const bool wr_ = ROWC ? (maskR[r] != 0) : true;
    const int drow = ROWC ? cposR[r] : r;
    f16* hrow = hi + (size_t)drow * DSTS;
    f16* lrow = lo + (size_t)drow * DSTS;
    double sls = 0, se2 = 0, smu2 = 0, sex = 0;
    for (int i = threadIdx.x; i < COLS / 4; i += 256) {
        float4 m = m4[i], l = l4[i], e = e4[i];
        float g0 = __expf(l.x), g1 = __expf(l.y), g2 = __expf(l.z), g3 = __expf(l.w);
        float w0 = fmaf(g0, e.x, m.x), w1 = fmaf(g1, e.y, m.y);
        float w2 = fmaf(g2, e.z, m.z), w3 = fmaf(g3, e.w, m.w);
        if (RED) {
            sls += (double)l.x + l.y + l.z + l.w;
            se2 += (double)e.x * e.x + (double)e.y * e.y + (double)e.z * e.z + (double)e.w * e.w;
            smu2 += (double)m.x * m.x + (double)m.y * m.y + (double)m.z * m.z + (double)m.w * m.w;
            sex += (double)g0 + g1 + g2 + g3;
        }
        if (wr_) {
            if (!COLC) {
                f16 h0 = (f16)w0, h1 = (f16)w1, h2 = (f16)w2, h3 = (f16)w3;
                f16x4 hv = {h0, h1, h2, h3};
                f16x4 lv = {(f16)(w0 - (float)h0), (f16)(w1 - (float)h1),
                            (f16)(w2 - (float)h2), (f16)(w3 - (float)h3)};
                *(f16x4*)(hrow + i * 4) = hv;
                *(f16x4*)(lrow + i * 4) = lv;
            } else {
                int4 mc = ((const int4*)maskC)[i];
                int4 cp = ((const int4*)cposC)[i];
                if (mc.x) { f16 h = (f16)w0; hrow[cp.x] = h; lrow[cp.x] = (f16)(w0 - (float)h); }
                if (mc.y) { f16 h = (f16)w1; hrow[cp.y] = h; lrow[cp.y] = (f16)(w1 - (float)h); }
                if (mc.z) { f16 h = (f16)w2; hrow[cp.z] = h; lrow[cp.z] = (f16)(w2 - (float)h); }
                if (mc.w) { f16 h = (f16)w3; hrow[cp.w] = h; lrow[cp.w] = (f16)(w3 - (float)h); }
            }
        }
    }
    if (RED) reduce4_atomic(sls, se2, smu2, sex, acc + 1, acc + 2, acc + 4, acc + 5);
}

// ---- split-f16 MFMA GEMM, 64x64 tile, BK=64, 4 waves, LDS double-buffer + counted vmcnt.
// EPI 0: bias+leaky+mask epilogue -> compact h hi/lo planes (zero-fill pad cols).
// EPI 1: raw partial f32 -> Cf[z][1024][1000] (split-K over blockIdx.z, bias added in CE).
template <int EPI>
__global__ __launch_bounds__(256, 2) void mgemm64(
    const f16* __restrict__ Ah, const f16* __restrict__ Al, int SA,
    const f16* __restrict__ Wh, const f16* __restrict__ Wl, int SW,
    const int* __restrict__ pN, int NFIX,
    const int* __restrict__ pK, int KFIX,
    const float* __restrict__ bsamp, const int* __restrict__ idx,
    const int* __restrict__ mz, const float* __restrict__ msum,
    f16* __restrict__ Chh, f16* __restrict__ Chl, int SC,
    float* __restrict__ Cf)
{
    const int nvalid = pN ? *pN : NFIX;
    const int bn = blockIdx.x * 64;
    if (bn >= nvalid) return;
    const int bm = blockIdx.y * 64;
    const int kvalid = pK ? *pK : KFIX;
    const int ktiles = (kvalid + 63) >> 6;
    int kt0 = 0, kt1 = ktiles;
    if (EPI == 1) {
        const int half = (ktiles + 1) >> 1;
        kt0 = blockIdx.z * half;
        kt1 = min(ktiles, kt0 + half);
    }

    __shared__ __align__(16) f16 lds[2][4][4096];
    const int tid = threadIdx.x;
    const int wv = tid >> 6, lane = tid & 63;
    const int wr = wv >> 1, wc = wv & 1;
    const int l15 = lane & 15, l4 = lane >> 4;

    // each wave stages one 64x64 f16 plane (8 x 1KB global_load_lds_dwordx4)
    const f16* src = (wv == 0) ? Ah : (wv == 1) ? Al : (wv == 2) ? Wh : Wl;
    const int S = (wv < 2) ? SA : SW;
    const int rowbase = (wv < 2) ? bm : bn;
    const f16* srcg[8];
#pragma unroll
    for (int g = 0; g < 8; ++g) {
        const int rb = g >> 1, kh = g & 1;
        srcg[g] = src + (size_t)(rowbase + rb * 16 + l15) * S + kh * 32 + l4 * 8;
    }

    f32x4 acc[2][2];
#pragma unroll
    for (int m = 0; m < 2; ++m)
#pragma unroll
        for (int n = 0; n < 2; ++n) acc[m][n] = (f32x4){0.f, 0.f, 0.f, 0.f};

    if (kt0 < kt1) {
#pragma unroll
        for (int g = 0; g < 8; ++g)
            gload_lds16(srcg[g] + (size_t)kt0 * 64, &lds[0][wv][g * 512]);
        asm volatile("s_waitcnt vmcnt(0)" ::: "memory");
        __builtin_amdgcn_s_barrier();
        __builtin_amdgcn_sched_barrier(0);
        int cur = 0;
        for (int kt = kt0; kt < kt1; ++kt) {
            if (kt + 1 < kt1) {
#pragma unroll
                for (int g = 0; g < 8; ++g)
                    gload_lds16(srcg[g] + (size_t)(kt + 1) * 64, &lds[cur ^ 1][wv][g * 512]);
                asm volatile("s_waitcnt vmcnt(8)" ::: "memory");
            } else {
                asm volatile("s_waitcnt vmcnt(0)" ::: "memory");
            }
            __builtin_amdgcn_s_barrier();
            __builtin_amdgcn_sched_barrier(0);
            const f16* L = &lds[cur][0][0];
#pragma unroll
            for (int kk = 0; kk < 2; ++kk) {
                f16x8 ah[2], al[2], wh[2], wl[2];
#pragma unroll
                for (int m = 0; m < 2; ++m) {
                    ah[m] = *(const f16x8*)(L + (2 * wr + m) * 1024 + kk * 512 + lane * 8);
                    al[m] = *(const f16x8*)(L + 4096 + (2 * wr + m) * 1024 + kk * 512 + lane * 8);
                }
#pragma unroll
                for (int n = 0; n < 2; ++n) {
                    wh[n] = *(const f16x8*)(L + 8192 + (2 * wc + n) * 1024 + kk * 512 + lane * 8);
                    wl[n] = *(const f16x8*)(L + 12288 + (2 * wc + n) * 1024 + kk * 512 + lane * 8);
                }
#pragma unroll
                for (int m = 0; m < 2; ++m)
#pragma unroll
                    for (int n = 0; n < 2; ++n)
                        acc[m][n] = __builtin_amdgcn_mfma_f32_16x16x32_f16(ah[m], wh[n], acc[m][n], 0, 0, 0);
#pragma unroll
                for (int m = 0; m < 2; ++m)
#pragma unroll
                    for (int n = 0; n < 2; ++n)
                        acc[m][n] = __builtin_amdgcn_mfma_f32_16x16x32_f16(ah[m], wl[n], acc[m][n], 0, 0, 0);
#pragma unroll
                for (int m = 0; m < 2; ++m)
#pragma unroll
                    for (int n = 0; n < 2; ++n)
                        acc[m][n] = __builtin_amdgcn_mfma_f32_16x16x32_f16(al[m], wh[n], acc[m][n], 0, 0, 0);
            }
            __builtin_amdgcn_sched_barrier(0);
            __builtin_amdgcn_s_barrier();
            __builtin_amdgcn_sched_barrier(0);
            cur ^= 1;
        }
    }

    // epilogue: C[row][col], col = bn + wc*32 + n*16 + (lane&15),
    // row = bm + wr*32 + m*16 + (lane>>4)*4 + j   (verified mapping from r2)
    if (EPI == 0) {
#pragma unroll
        for (int n = 0; n < 2; ++n) {
            const int c = bn + wc * 32 + n * 16 + l15;
            const bool cv = c < nvalid;
            const int orig = cv ? idx[c] : 0;
            const float bias = cv ? bsamp[orig] : 0.f;
#pragma unroll
            for (int m = 0; m < 2; ++m) {
#pragma unroll
                for (int j = 0; j < 4; ++j) {
                    const int row = bm + wr * 32 + m * 16 + l4 * 4 + j;
                    float v = acc[m][n][j] + bias;
                    v = v >= 0.f ? v : 0.01f * v;
                    if (cv) {
                        const int mm = mz[(size_t)row * 4096 + orig];
                        const float mult = 4096.0f / (msum[row] + 1e-6f);
                        v = v * (float)mm * mult;
                    } else {
                        v = 0.f;
                    }
                    const f16 hh = (f16)v;
                    Chh[(size_t)row * SC + c] = hh;
                    Chl[(size_t)row * SC + c] = (f16)(v - (float)hh);
                }
            }
        }
    } else {
#pragma unroll
        for (int n = 0; n < 2; ++n) {
            const int c = bn + wc * 32 + n * 16 + l15;
            if (c >= NFIX) continue;
#pragma unroll
            for (int m = 0; m < 2; ++m)
#pragma unroll
                for (int j = 0; j < 4; ++j) {
                    const int row = bm + wr * 32 + m * 16 + l4 * 4 + j;
                    Cf[(size_t)blockIdx.z * (B_SZ * OUT_SZ) + (size_t)row * OUT_SZ + c] = acc[m][n][j];
                }
        }
    }
}

// ---- CE over 2 split-K partials + sampled bias; writes pred; acc[6] += lse - pred[y]
__global__ __launch_bounds__(256) void ce_fused2_kernel(const float* __restrict__ part,
                                                        const float* __restrict__ bso,
                                                        const int* __restrict__ y,
                                                        float* __restrict__ pred, double* acc)
{
    const int b = blockIdx.x;
    const size_t PS = (size_t)B_SZ * OUT_SZ;
    float mx = -1e30f;
    for (int j = threadIdx.x; j < OUT_SZ; j += 256) {
        const size_t o = (size_t)b * OUT_SZ + j;
        float v = part[o] + part[o + PS] + bso[j];
        pred[o] = v;
        mx = fmaxf(mx, v);
    }
#pragma unroll
    for (int o = 32; o > 0; o >>= 1) mx = fmaxf(mx, __shfl_down(mx, o, 64));
    __shared__ float sm[4];
    if ((threadIdx.x & 63) == 0) sm[threadIdx.x >> 6] = mx;
    __syncthreads();
    mx = fmaxf(fmaxf(sm[0], sm[1]), fmaxf(sm[2], sm[3]));
    double se = 0;
    for (int j = threadIdx.x; j < OUT_SZ; j += 256)
        se += (double)__expf(pred[(size_t)b * OUT_SZ + j] - mx);
#pragma unroll
    for (int o = 32; o > 0; o >>= 1) se += __shfl_down(se, o, 64);
    __shared__ double sd[4];
    if ((threadIdx.x & 63) == 0) sd[threadIdx.x >> 6] = se;
    __syncthreads();
    if (threadIdx.x == 0) {
        double lse = (double)mx + log(sd[0] + sd[1] + sd[2] + sd[3]);
        atomicAdd(acc + 6, lse - (double)pred[(size_t)b * OUT_SZ + y[b]]);
    }
}

__global__ void finalize_kernel(const double* __restrict__ acc, const int* __restrict__ dss,
                                float* __restrict__ out)
{
    const double NTOT = 25174016.0;  // W0 + b0 + W1 + b1 element count
    double cst = NTOT * (log(2.0e-5) - 0.91893853320467274178);
    double loss = acc[0]
                + cst - acc[1] - 0.5 * acc[2]
                + acc[3]
                + (double)(*dss) * (acc[6] / (double)B_SZ)
                + 0.01 * (acc[4] + acc[5]);
    out[(size_t)B_SZ * OUT_SZ] = (float)(loss * loss);
}

extern "C" void kernel_launch(void* const* d_in, const int* in_sizes, int n_in,
                              void* d_out, int out_size, void* d_ws, size_t ws_size,
                              hipStream_t stream)
{
    const float* x = (const float*)d_in[0];
    const float* zw = (const float*)d_in[1];
    const float* wmu0 = (const float*)d_in[2];
    const float* wls0 = (const float*)d_in[3];
    const float* bmu0 = (const float*)d_in[4];
    const float* bls0 = (const float*)d_in[5];
    const float* weps0 = (const float*)d_in[6];
    const float* beps0 = (const float*)d_in[7];
    const float* wmu1 = (const float*)d_in[8];
    const float* wls1 = (const float*)d_in[9];
    const float* bmu1 = (const float*)d_in[10];
    const float* bls1 = (const float*)d_in[11];
    const float* weps1 = (const float*)d_in[12];
    const float* beps1 = (const float*)d_in[13];
    const float* wmuo = (const float*)d_in[14];
    const float* wlso = (const float*)d_in[15];
    const float* bmuo = (const float*)d_in[16];
    const float* blso = (const float*)d_in[17];
    const float* wepso = (const float*)d_in[18];
    const float* bepso = (const float*)d_in[19];
    const float* pfz0 = (const float*)d_in[20];
    const float* pfz1 = (const float*)d_in[21];
    const int* y = (const int*)d_in[22];
    const int* mz0 = (const int*)d_in[23];
    const int* mz1 = (const int*)d_in[24];
    const int* mmu0 = (const int*)d_in[25];
    const int* mmu1 = (const int*)d_in[26];
    const int* dss = (const int*)d_in[27];

    char* ws = (char*)d_ws;
    double* acc = (double*)ws;
    int* n0p = (int*)(ws + OFF_N0);
    int* n1p = (int*)(ws + OFF_N1);
    float* msum0 = (float*)(ws + OFF_MSUM0);
    float* msum1 = (float*)(ws + OFF_MSUM1);
    int* cpos0 = (int*)(ws + OFF_CPOS0);
    int* cpos1 = (int*)(ws + OFF_CPOS1);
    int* idx0 = (int*)(ws + OFF_IDX0);
    int* idx1 = (int*)(ws + OFF_IDX1);
    float* bs0 = (float*)(ws + OFF_BS0);
    float* bs1 = (float*)(ws + OFF_BS1);
    float* bso = (float*)(ws + OFF_BSO);
    f16* xh = (f16*)(ws + OFF_XH);
    f16* xl = (f16*)(ws + OFF_XL);
    f16* h0h = (f16*)(ws + OFF_H0H);
    f16* h0l = (f16*)(ws + OFF_H0L);
    f16* h1h = (f16*)(ws + OFF_H1H);
    f16* h1l = (f16*)(ws + OFF_H1L);
    f16* w0ch = (f16*)(ws + OFF_W0CH);
    f16* w0cl = (f16*)(ws + OFF_W0CL);
    f16* w1ch = (f16*)(ws + OFF_W1CH);
    f16* w1cl = (f16*)(ws + OFF_W1CL);
    f16* woch = (f16*)(ws + OFF_WOCH);
    f16* wocl = (f16*)(ws + OFF_WOCL);
    float* part = (float*)(ws + OFF_PART);
    float* out = (float*)d_out;

    hipMemsetAsync(ws, 0, 72, stream);

    idxbuild_kernel<<<1, 1024, 0, stream>>>(mmu0, mmu1, cpos0, idx0, n0p, cpos1, idx1, n1p);
    splitx_kernel<<<1024, 256, 0, stream>>>((const float4*)x, (const float4*)zw,
                                            (f16x4*)xh, (f16x4*)xl, acc);
    flowmsum_kernel<<<B_SZ, 256, 0, stream>>>(mz0, pfz0, mmu0, msum0, acc);
    flowmsum_kernel<<<B_SZ, 256, 0, stream>>>(mz1, pfz1, mmu1, msum1, acc);
    bsample_kernel<1><<<16, 256, 0, stream>>>(bmu0, bls0, beps0, bs0, H0_SZ, acc);
    bsample_kernel<1><<<16, 256, 0, stream>>>(bmu1, bls1, beps1, bs1, H1_SZ, acc);
    bsample_kernel<0><<<4, 256, 0, stream>>>(bmuo, blso, bepso, bso, OUT_SZ, acc);

    wsample_kernel<IN_SZ, 1, 0, 1><<<H0_SZ, 256, 0, stream>>>(
        wmu0, wls0, weps0, mmu0, cpos0, nullptr, nullptr, w0ch, w0cl, IN_SZ, acc);
    wsample_kernel<H0_SZ, 1, 1, 1><<<H1_SZ, 256, 0, stream>>>(
        wmu1, wls1, weps1, mmu1, cpos1, mmu0, cpos0, w1ch, w1cl, 4096, acc);
    wsample_kernel<H1_SZ, 0, 1, 0><<<OUT_SZ, 256, 0, stream>>>(
        wmuo, wlso, wepso, nullptr, nullptr, mmu1, cpos1, woch, wocl, 4096, acc);

    // layer 0: A = x planes [1024][2048], W = W0 compact [n0][2048], out h0 compact
    mgemm64<0><<<dim3(64, 16), 256, 0, stream>>>(
        xh, xl, IN_SZ, w0ch, w0cl, IN_SZ, n0p, 0, nullptr, IN_SZ,
        bs0, idx0, mz0, msum0, h0h, h0l, 4096, nullptr);
    // layer 1: A = h0 compact [1024][n0], W = W1 compact [n1][n0], out h1 compact
    mgemm64<0><<<dim3(64, 16), 256, 0, stream>>>(
        h0h, h0l, 4096, w1ch, w1cl, 4096, n1p, 0, n0p, 0,
        bs1, idx1, mz1, msum1, h1h, h1l, 4096, nullptr);
    // out layer: A = h1 compact, W = Wo compact [1000][n1], split-K=2 partials
    mgemm64<1><<<dim3(16, 16, 2), 256, 0, stream>>>(
        h1h, h1l, 4096, woch, wocl, 4096, nullptr, OUT_SZ, n1p, 0,
        nullptr, nullptr, nullptr, nullptr, nullptr, nullptr, 0, part);

    ce_fused2_kernel<<<B_SZ, 256, 0, stream>>>(part, bso, y, out, acc);
    finalize_kernel<<<1, 1, 0, stream>>>(acc, dss, out);
}

// Round 5
// 390.453 us; speedup vs baseline: 1.9633x; 1.9633x over previous
//
#include <hip/hip_runtime.h>
#include <math.h>

#define B_SZ 1024
#define IN_SZ 2048
#define H0_SZ 4096
#define H1_SZ 4096
#define OUT_SZ 1000

typedef _Float16 f16;
typedef __attribute__((ext_vector_type(4))) _Float16 f16x4;
typedef __attribute__((ext_vector_type(8))) _Float16 f16x8;
typedef __attribute__((ext_vector_type(4))) float f32x4;

// ---------------- ws layout (bytes) ----------------
// r4 bug: PW (8192 slots x 32B = 262144B, ends 369920) overlapped BS0@364544.
// Layout re-flowed; every offset below is start, with stated end.
#define OFF_N0     0ULL
#define OFF_N1     4ULL
#define OFF_MSUM0  256ULL        // -> 4352
#define OFF_MSUM1  4352ULL       // -> 8448
#define OFF_CPOS0  8448ULL       // -> 24832
#define OFF_CPOS1  24832ULL      // -> 41216
#define OFF_IDX0   41216ULL      // -> 57600
#define OFF_IDX1   57600ULL      // -> 73984
#define OFF_PXZ    73984ULL      // 1024 dbl -> 82176
#define OFF_PFL    82176ULL      // 2048 dbl -> 98560
#define OFF_PCE    98560ULL      // 1024 dbl -> 106752
#define OFF_PB     106752ULL     // 32x4 dbl -> 107776
#define OFF_PW     107776ULL     // 8192x4 dbl -> 369920
#define OFF_BS0    370688ULL     // -> 387072
#define OFF_BS1    387072ULL     // -> 403456
#define OFF_BSO    403456ULL     // -> 407552
#define OFF_XH     407552ULL     // +4194304 -> 4601856
#define OFF_XL     4601856ULL    // -> 8796160
#define OFF_H0H    8796160ULL    // +8388608 -> 17184768
#define OFF_H0L    17184768ULL   // -> 25573376
#define OFF_H1H    25573376ULL   // -> 33961984
#define OFF_H1L    33961984ULL   // -> 42350592
#define OFF_W0CH   42350592ULL   // +16777216 -> 59127808
#define OFF_W0CL   59127808ULL   // -> 75905024
#define OFF_W1CH   75905024ULL   // +33554432 -> 109459456
#define OFF_W1CL   109459456ULL  // -> 143013888
#define OFF_WOCH   143013888ULL  // +8388608 -> 151402496
#define OFF_WOCL   151402496ULL  // -> 159791104
#define OFF_PART   159791104ULL  // +8192000 -> 167983104 (< ws_size >= 175783936)

__device__ __forceinline__ void gload_lds16(const void* g, void* l)
{
    __builtin_amdgcn_global_load_lds((const __attribute__((address_space(1))) void*)g,
                                     (__attribute__((address_space(3))) void*)l, 16, 0, 0);
}

// block-reduce 4 doubles; thread 0 stores them to dst[0..3] (plain stores, no atomics)
__device__ __forceinline__ void reduce4_store(double v0, double v1, double v2, double v3,
                                              double* dst)
{
    __shared__ double sh[4][4];
    double v[4] = {v0, v1, v2, v3};
    int lane = threadIdx.x & 63, wid = threadIdx.x >> 6;
#pragma unroll
    for (int a = 0; a < 4; ++a) {
        double x = v[a];
#pragma unroll
        for (int o = 32; o > 0; o >>= 1) x += __shfl_down(x, o, 64);
        if (lane == 0) sh[a][wid] = x;
    }
    __syncthreads();
    if (threadIdx.x == 0) {
        dst[0] = sh[0][0] + sh[0][1] + sh[0][2] + sh[0][3];
        dst[1] = sh[1][0] + sh[1][1] + sh[1][2] + sh[1][3];
        dst[2] = sh[2][0] + sh[2][1] + sh[2][2] + sh[2][3];
        dst[3] = sh[3][0] + sh[3][1] + sh[3][2] + sh[3][3];
    }
}

__device__ __forceinline__ void reduce1_store(double v, double* dst)
{
    __shared__ double sh1[4];
    int lane = threadIdx.x & 63, wid = threadIdx.x >> 6;
#pragma unroll
    for (int o = 32; o > 0; o >>= 1) v += __shfl_down(v, o, 64);
    if (lane == 0) sh1[wid] = v;
    __syncthreads();
    if (threadIdx.x == 0) dst[0] = sh1[0] + sh1[1] + sh1[2] + sh1[3];
}

// ---- build compaction maps: cpos (exclusive prefix), idx (compact->orig), n
__global__ __launch_bounds__(1024) void idxbuild_kernel(
    const int* __restrict__ mask0, const int* __restrict__ mask1,
    int* __restrict__ cpos0, int* __restrict__ idx0, int* __restrict__ n0,
    int* __restrict__ cpos1, int* __restrict__ idx1, int* __restrict__ n1)
{
    __shared__ int sh[1024];
    const int t = threadIdx.x;
    for (int pass = 0; pass < 2; ++pass) {
        const int* mask = pass ? mask1 : mask0;
        int* cpos = pass ? cpos1 : cpos0;
        int* idx = pass ? idx1 : idx0;
        int* np = pass ? n1 : n0;
        int4 m = ((const int4*)mask)[t];
        int s = m.x + m.y + m.z + m.w;
        sh[t] = s;
        __syncthreads();
        for (int o = 1; o < 1024; o <<= 1) {
            int v = (t >= o) ? sh[t - o] : 0;
            __syncthreads();
            sh[t] += v;
            __syncthreads();
        }
        int run = sh[t] - s;
        int4 cp;
        cp.x = run; cp.y = run + m.x; cp.z = cp.y + m.y; cp.w = cp.z + m.z;
        ((int4*)cpos)[t] = cp;
        if (m.x) idx[cp.x] = 4 * t + 0;
        if (m.y) idx[cp.y] = 4 * t + 1;
        if (m.z) idx[cp.z] = 4 * t + 2;
        if (m.w) idx[cp.w] = 4 * t + 3;
        if (t == 1023) *np = sh[1023];
        __syncthreads();
    }
}

// ---- split x into f16 hi/lo planes, fused with (x @ z_w).sum() partial
__global__ __launch_bounds__(256) void splitx_kernel(const float4* __restrict__ x,
                                                     const float4* __restrict__ zw,
                                                     f16x4* __restrict__ xh, f16x4* __restrict__ xl,
                                                     double* __restrict__ pxz)
{
    const int n4 = B_SZ * IN_SZ / 4;
    double s = 0;
    int i = blockIdx.x * blockDim.x + threadIdx.x;
    int stride = gridDim.x * blockDim.x;
    for (; i < n4; i += stride) {
        float4 v = x[i];
        float4 z = zw[i & (IN_SZ / 4 - 1)];
        s += (double)v.x * z.x + (double)v.y * z.y + (double)v.z * z.z + (double)v.w * z.w;
        f16 h0 = (f16)v.x, h1 = (f16)v.y, h2 = (f16)v.z, h3 = (f16)v.w;
        f16x4 hv = {h0, h1, h2, h3};
        f16x4 lv = {(f16)(v.x - (float)h0), (f16)(v.y - (float)h1),
                    (f16)(v.z - (float)h2), (f16)(v.w - (float)h3)};
        xh[i] = hv; xl[i] = lv;
    }
    reduce1_store(s, pxz + blockIdx.x);
}

// ---- fused GFN flow + per-row mask sum (one block per batch row); partial store
__global__ __launch_bounds__(256) void flowmsum_kernel(const int* __restrict__ mz,
                                                       const float* __restrict__ pfz,
                                                       const int* __restrict__ maskmu,
                                                       float* __restrict__ msum,
                                                       double* __restrict__ pfl)
{
    const int b = blockIdx.x;
    const int4* m4 = (const int4*)(mz + (size_t)b * 4096);
    const float4* p4 = (const float4*)(pfz + (size_t)b * 4096);
    const int4* k4 = (const int4*)maskmu;
    int s = 0;
    double fl = 0;
    for (int i = threadIdx.x; i < 1024; i += 256) {
        int4 m = m4[i];
        float4 p = p4[i];
        int4 k = k4[i];
        s += m.x * k.x + m.y * k.y + m.z * k.z + m.w * k.w;
        float a0 = fminf(fmaxf(p.x, 1e-6f), 1.0f - 1e-6f);
        float a1 = fminf(fmaxf(p.y, 1e-6f), 1.0f - 1e-6f);
        float a2 = fminf(fmaxf(p.z, 1e-6f), 1.0f - 1e-6f);
        float a3 = fminf(fmaxf(p.w, 1e-6f), 1.0f - 1e-6f);
        fl += (double)logf(m.x ? a0 : 1.0f - a0);
        fl += (double)logf(m.y ? a1 : 1.0f - a1);
        fl += (double)logf(m.z ? a2 : 1.0f - a2);
        fl += (double)logf(m.w ? a3 : 1.0f - a3);
    }
#pragma unroll
    for (int o = 32; o > 0; o >>= 1) {
        s += __shfl_down(s, o, 64);
        fl += __shfl_down(fl, o, 64);
    }
    __shared__ int shi[4];
    __shared__ double shd[4];
    if ((threadIdx.x & 63) == 0) { shi[threadIdx.x >> 6] = s; shd[threadIdx.x >> 6] = fl; }
    __syncthreads();
    if (threadIdx.x == 0) {
        msum[b] = (float)(shi[0] + shi[1] + shi[2] + shi[3]);
        pfl[b] = shd[0] + shd[1] + shd[2] + shd[3];
    }
}

// ---- sample biases (+ optional partial reductions into pb slot)
template <int RED>
__global__ __launch_bounds__(256) void bsample_kernel(const float* __restrict__ bmu,
                                                      const float* __restrict__ bls,
                                                      const float* __restrict__ beps,
                                                      float* __restrict__ out, int n,
                                                      double* __restrict__ pb)
{
    int i = blockIdx.x * 256 + threadIdx.x;
    float l = 0.f, e = 0.f;
    if (i < n) {
        l = bls[i]; e = beps[i];
        out[i] = fmaf(__expf(l), e, bmu[i]);
    }
    if (RED) {
        double sls = (i < n) ? (double)l : 0.0;
        double se2 = (i < n) ? (double)e * e : 0.0;
        reduce4_store(sls, se2, 0.0, 0.0, pb + (size_t)blockIdx.x * 4);
    }
}

// ---- W0: sample + row-compact, vectorized stores, partial reductions
__global__ __launch_bounds__(256) void wsample_rowc_kernel(
    const float* __restrict__ mu, const float* __restrict__ ls, const float* __restrict__ eps,
    const int* __restrict__ maskR, const int* __restrict__ cposR,
    f16* __restrict__ hi, f16* __restrict__ lo, double* __restrict__ pw)
{
    const int r = blockIdx.x;
    const size_t rb = (size_t)r * IN_SZ;
    const float4* m4 = (const float4*)(mu + rb);
    const float4* l4 = (const float4*)(ls + rb);
    const float4* e4 = (const float4*)(eps + rb);
    const bool wr_ = maskR[r] != 0;
    const int drow = cposR[r];
    f16* hrow = hi + (size_t)drow * IN_SZ;
    f16* lrow = lo + (size_t)drow * IN_SZ;
    double sls = 0, se2 = 0, smu2 = 0, sex = 0;
    for (int i = threadIdx.x; i < IN_SZ / 4; i += 256) {
        float4 m = m4[i], l = l4[i], e = e4[i];
        float g0 = __expf(l.x), g1 = __expf(l.y), g2 = __expf(l.z), g3 = __expf(l.w);
        float w0 = fmaf(g0, e.x, m.x), w1 = fmaf(g1, e.y, m.y);
        float w2 = fmaf(g2, e.z, m.z), w3 = fmaf(g3, e.w, m.w);
        sls += (double)l.x + l.y + l.z + l.w;
        se2 += (double)e.x * e.x + (double)e.y * e.y + (double)e.z * e.z + (double)e.w * e.w;
        smu2 += (double)m.x * m.x + (double)m.y * m.y + (double)m.z * m.z + (double)m.w * m.w;
        sex += (double)g0 + g1 + g2 + g3;
        if (wr_) {
            f16 h0 = (f16)w0, h1 = (f16)w1, h2 = (f16)w2, h3 = (f16)w3;
            f16x4 hv = {h0, h1, h2, h3};
            f16x4 lv = {(f16)(w0 - (float)h0), (f16)(w1 - (float)h1),
                        (f16)(w2 - (float)h2), (f16)(w3 - (float)h3)};
            *(f16x4*)(hrow + i * 4) = hv;
            *(f16x4*)(lrow + i * 4) = lv;
        }
    }
    reduce4_store(sls, se2, smu2, sex, pw + (size_t)r * 4);
}

// ---- W1/Wo: sample + optional row-compact + column-compact via LDS staging.
template <int ROWC, int RED>
__global__ __launch_bounds__(256) void wsample_colc_kernel(
    const float* __restrict__ mu, const float* __restrict__ ls, const float* __restrict__ eps,
    const int* __restrict__ maskR, const int* __restrict__ cposR,
    const int* __restrict__ maskC, const int* __restrict__ cposC, const int* __restrict__ pNc,
    f16* __restrict__ hi, f16* __restrict__ lo, double* __restrict__ pw)
{
    __shared__ __align__(16) f16 ldsH[4096];
    __shared__ __align__(16) f16 ldsL[4096];
    const int r = blockIdx.x;
    const size_t rb = (size_t)r * 4096;
    const float4* m4 = (const float4*)(mu + rb);
    const float4* l4 = (const float4*)(ls + rb);
    const float4* e4 = (const float4*)(eps + rb);
    const bool wr_ = ROWC ? (maskR[r] != 0) : true;
    const int drow = ROWC ? cposR[r] : r;
    const int t = threadIdx.x;
    const f16x8 z8 = {0, 0, 0, 0, 0, 0, 0, 0};
    for (int i = t; i < 512; i += 256) {
        ((f16x8*)ldsH)[i] = z8;
        ((f16x8*)ldsL)[i] = z8;
    }
    __syncthreads();
    double sls = 0, se2 = 0, smu2 = 0, sex = 0;
    for (int i = t; i < 1024; i += 256) {
        float4 m = m4[i], l = l4[i], e = e4[i];
        float g0 = __expf(l.x), g1 = __expf(l.y), g2 = __expf(l.z), g3 = __expf(l.w);
        float w0 = fmaf(g0, e.x, m.x), w1 = fmaf(g1, e.y, m.y);
        float w2 = fmaf(g2, e.z, m.z), w3 = fmaf(g3, e.w, m.w);
        if (RED) {
            sls += (double)l.x + l.y + l.z + l.w;
            se2 += (double)e.x * e.x + (double)e.y * e.y + (double)e.z * e.z + (double)e.w * e.w;
            smu2 += (double)m.x * m.x + (double)m.y * m.y + (double)m.z * m.z + (double)m.w * m.w;
            sex += (double)g0 + g1 + g2 + g3;
        }
        if (wr_) {
            int4 mc = ((const int4*)maskC)[i];
            int4 cp = ((const int4*)cposC)[i];
            if (mc.x) { f16 h = (f16)w0; ldsH[cp.x] = h; ldsL[cp.x] = (f16)(w0 - (float)h); }
            if (mc.y) { f16 h = (f16)w1; ldsH[cp.y] = h; ldsL[cp.y] = (f16)(w1 - (float)h); }
            if (mc.z) { f16 h = (f16)w2; ldsH[cp.z] = h; ldsL[cp.z] = (f16)(w2 - (float)h); }
            if (mc.w) { f16 h = (f16)w3; ldsH[cp.w] = h; ldsL[cp.w] = (f16)(w3 - (float)h); }
        }
    }
    __syncthreads();
    if (wr_) {
        const int n8 = (*pNc + 7) >> 3;
        f16x8* hd = (f16x8*)(hi + (size_t)drow * 4096);
        f16x8* ld = (f16x8*)(lo + (size_t)drow * 4096);
        for (int i = t; i < n8; i += 256) {
            hd[i] = ((const f16x8*)ldsH)[i];
            ld[i] = ((const f16x8*)ldsL)[i];
        }
    }
    if (RED) reduce4_store(sls, se2, smu2, sex, pw + (size_t)r * 4);
}

// ---- split-f16 MFMA GEMM, 64x64 tile, BK=64, 4 waves, LDS dbuf + counted vmcnt.
template <int EPI>
__global__ __launch_bounds__(256, 2) void mgemm64(
    const f16* __restrict__ Ah, const f16* __restrict__ Al, int SA,
    const f16* __restrict__ Wh, const f16* __restrict__ Wl, int SW,
    const int* __restrict__ pN, int NFIX,
    const int* __restrict__ pK, int KFIX,
    const float* __restrict__ bsamp, const int* __restrict__ idx,
    const int* __restrict__ mz, const float* __restrict__ msum,
    f16* __restrict__ Chh, f16* __restrict__ Chl, int SC,
    float* __restrict__ Cf)
{
    const int nvalid = pN ? *pN : NFIX;
    const int bn = blockIdx.x * 64;
    if (bn >= nvalid) return;
    const int bm = blockIdx.y * 64;
    const int kvalid = pK ? *pK : KFIX;
    const int ktiles = (kvalid + 63) >> 6;
    int kt0 = 0, kt1 = ktiles;
    if (EPI == 1) {
        const int half = (ktiles + 1) >> 1;
        kt0 = blockIdx.z * half;
        kt1 = min(ktiles, kt0 + half);
    }

    __shared__ __align__(16) f16 lds[2][4][4096];
    const int tid = threadIdx.x;
    const int wv = tid >> 6, lane = tid & 63;
    const int wr = wv >> 1, wc = wv & 1;
    const int l15 = lane & 15, l4 = lane >> 4;

    const f16* src = (wv == 0) ? Ah : (wv == 1) ? Al : (wv == 2) ? Wh : Wl;
    const int S = (wv < 2) ? SA : SW;
    const int rowbase = (wv < 2) ? bm : bn;
    const f16* srcg[8];
#pragma unroll
    for (int g = 0; g < 8; ++g) {
        const int rb = g >> 1, kh = g & 1;
        srcg[g] = src + (size_t)(rowbase + rb * 16 + l15) * S + kh * 32 + l4 * 8;
    }

    f32x4 acc[2][2];
#pragma unroll
    for (int m = 0; m < 2; ++m)
#pragma unroll
        for (int n = 0; n < 2; ++n) acc[m][n] = (f32x4){0.f, 0.f, 0.f, 0.f};

    if (kt0 < kt1) {
#pragma unroll
        for (int g = 0; g < 8; ++g)
            gload_lds16(srcg[g] + (size_t)kt0 * 64, &lds[0][wv][g * 512]);
        asm volatile("s_waitcnt vmcnt(0)" ::: "memory");
        __builtin_amdgcn_s_barrier();
        __builtin_amdgcn_sched_barrier(0);
        int cur = 0;
        for (int kt = kt0; kt < kt1; ++kt) {
            if (kt + 1 < kt1) {
#pragma unroll
                for (int g = 0; g < 8; ++g)
                    gload_lds16(srcg[g] + (size_t)(kt + 1) * 64, &lds[cur ^ 1][wv][g * 512]);
                asm volatile("s_waitcnt vmcnt(8)" ::: "memory");
            } else {
                asm volatile("s_waitcnt vmcnt(0)" ::: "memory");
            }
            __builtin_amdgcn_s_barrier();
            __builtin_amdgcn_sched_barrier(0);
            const f16* L = &lds[cur][0][0];
#pragma unroll
            for (int kk = 0; kk < 2; ++kk) {
                f16x8 ah[2], al[2], wh[2], wl[2];
#pragma unroll
                for (int m = 0; m < 2; ++m) {
                    ah[m] = *(const f16x8*)(L + (2 * wr + m) * 1024 + kk * 512 + lane * 8);
                    al[m] = *(const f16x8*)(L + 4096 + (2 * wr + m) * 1024 + kk * 512 + lane * 8);
                }
#pragma unroll
                for (int n = 0; n < 2; ++n) {
                    wh[n] = *(const f16x8*)(L + 8192 + (2 * wc + n) * 1024 + kk * 512 + lane * 8);
                    wl[n] = *(const f16x8*)(L + 12288 + (2 * wc + n) * 1024 + kk * 512 + lane * 8);
                }
#pragma unroll
                for (int m = 0; m < 2; ++m)
#pragma unroll
                    for (int n = 0; n < 2; ++n)
                        acc[m][n] = __builtin_amdgcn_mfma_f32_16x16x32_f16(ah[m], wh[n], acc[m][n], 0, 0, 0);
#pragma unroll
                for (int m = 0; m < 2; ++m)
#pragma unroll
                    for (int n = 0; n < 2; ++n)
                        acc[m][n] = __builtin_amdgcn_mfma_f32_16x16x32_f16(ah[m], wl[n], acc[m][n], 0, 0, 0);
#pragma unroll
                for (int m = 0; m < 2; ++m)
#pragma unroll
                    for (int n = 0; n < 2; ++n)
                        acc[m][n] = __builtin_amdgcn_mfma_f32_16x16x32_f16(al[m], wh[n], acc[m][n], 0, 0, 0);
            }
            __builtin_amdgcn_sched_barrier(0);
            __builtin_amdgcn_s_barrier();
            __builtin_amdgcn_sched_barrier(0);
            cur ^= 1;
        }
    }

    if (EPI == 0) {
#pragma unroll
        for (int n = 0; n < 2; ++n) {
            const int c = bn + wc * 32 + n * 16 + l15;
            const bool cv = c < nvalid;
            const int orig = cv ? idx[c] : 0;
            const float bias = cv ? bsamp[orig] : 0.f;
#pragma unroll
            for (int m = 0; m < 2; ++m) {
#pragma unroll
                for (int j = 0; j < 4; ++j) {
                    const int row = bm + wr * 32 + m * 16 + l4 * 4 + j;
                    float v = acc[m][n][j] + bias;
                    v = v >= 0.f ? v : 0.01f * v;
                    if (cv) {
                        const int mm = mz[(size_t)row * 4096 + orig];
                        const float mult = 4096.0f / (msum[row] + 1e-6f);
                        v = v * (float)mm * mult;
                    } else {
                        v = 0.f;
                    }
                    const f16 hh = (f16)v;
                    Chh[(size_t)row * SC + c] = hh;
                    Chl[(size_t)row * SC + c] = (f16)(v - (float)hh);
                }
            }
        }
    } else {
#pragma unroll
        for (int n = 0; n < 2; ++n) {
            const int c = bn + wc * 32 + n * 16 + l15;
            if (c >= NFIX) continue;
#pragma unroll
            for (int m = 0; m < 2; ++m)
#pragma unroll
                for (int j = 0; j < 4; ++j) {
                    const int row = bm + wr * 32 + m * 16 + l4 * 4 + j;
                    Cf[(size_t)blockIdx.z * (B_SZ * OUT_SZ) + (size_t)row * OUT_SZ + c] = acc[m][n][j];
                }
        }
    }
}

// ---- CE over 2 split-K partials + sampled bias; partial store of lse - pred[y]
__global__ __launch_bounds__(256) void ce_fused2_kernel(const float* __restrict__ part,
                                                        const float* __restrict__ bso,
                                                        const int* __restrict__ y,
                                                        float* __restrict__ pred,
                                                        double* __restrict__ pce)
{
    const int b = blockIdx.x;
    const size_t PS = (size_t)B_SZ * OUT_SZ;
    float mx = -1e30f;
    for (int j = threadIdx.x; j < OUT_SZ; j += 256) {
        const size_t o = (size_t)b * OUT_SZ + j;
        float v = part[o] + part[o + PS] + bso[j];
        pred[o] = v;
        mx = fmaxf(mx, v);
    }
#pragma unroll
    for (int o = 32; o > 0; o >>= 1) mx = fmaxf(mx, __shfl_down(mx, o, 64));
    __shared__ float sm[4];
    if ((threadIdx.x & 63) == 0) sm[threadIdx.x >> 6] = mx;
    __syncthreads();
    mx = fmaxf(fmaxf(sm[0], sm[1]), fmaxf(sm[2], sm[3]));
    double se = 0;
    for (int j = threadIdx.x; j < OUT_SZ; j += 256)
        se += (double)__expf(pred[(size_t)b * OUT_SZ + j] - mx);
#pragma unroll
    for (int o = 32; o > 0; o >>= 1) se += __shfl_down(se, o, 64);
    __shared__ double sd[4];
    if ((threadIdx.x & 63) == 0) sd[threadIdx.x >> 6] = se;
    __syncthreads();
    if (threadIdx.x == 0) {
        double lse = (double)mx + log(sd[0] + sd[1] + sd[2] + sd[3]);
        pce[b] = lse - (double)pred[(size_t)b * OUT_SZ + y[b]];
    }
}

// ---- final: sum all partials, assemble loss, square
__global__ __launch_bounds__(256) void finalize_kernel(
    const double* __restrict__ PXZ, const double* __restrict__ PFL,
    const double* __restrict__ PCE, const double* __restrict__ PB,
    const double* __restrict__ PW, const int* __restrict__ dss, float* __restrict__ out)
{
    const int t = threadIdx.x;
    double xz = 0, fl = 0, ce = 0, ls = 0, e2 = 0, mu2 = 0, ex = 0;
    for (int i = t; i < 1024; i += 256) xz += PXZ[i];
    for (int i = t; i < 2048; i += 256) fl += PFL[i];
    for (int i = t; i < 1024; i += 256) ce += PCE[i];
    for (int i = t; i < 8192; i += 256) {
        const double* p = PW + (size_t)i * 4;
        ls += p[0]; e2 += p[1]; mu2 += p[2]; ex += p[3];
    }
    if (t < 32) { ls += PB[t * 4]; e2 += PB[t * 4 + 1]; }
    __shared__ double sh[7][4];
    double v[7] = {xz, fl, ce, ls, e2, mu2, ex};
    const int lane = t & 63, wid = t >> 6;
#pragma unroll
    for (int a = 0; a < 7; ++a) {
        double x = v[a];
#pragma unroll
        for (int o = 32; o > 0; o >>= 1) x += __shfl_down(x, o, 64);
        if (lane == 0) sh[a][wid] = x;
    }
    __syncthreads();
    if (t == 0) {
        double T[7];
#pragma unroll
        for (int a = 0; a < 7; ++a) T[a] = sh[a][0] + sh[a][1] + sh[a][2] + sh[a][3];
        const double NTOT = 25174016.0;  // W0 + b0 + W1 + b1 element count
        double cst = NTOT * (log(2.0e-5) - 0.91893853320467274178);
        double loss = T[0]
                    + cst - T[3] - 0.5 * T[4]
                    + T[1]
                    + (double)(*dss) * (T[2] / (double)B_SZ)
                    + 0.01 * (T[5] + T[6]);
        out[(size_t)B_SZ * OUT_SZ] = (float)(loss * loss);
    }
}

extern "C" void kernel_launch(void* const* d_in, const int* in_sizes, int n_in,
                              void* d_out, int out_size, void* d_ws, size_t ws_size,
                              hipStream_t stream)
{
    const float* x = (const float*)d_in[0];
    const float* zw = (const float*)d_in[1];
    const float* wmu0 = (const float*)d_in[2];
    const float* wls0 = (const float*)d_in[3];
    const float* bmu0 = (const float*)d_in[4];
    const float* bls0 = (const float*)d_in[5];
    const float* weps0 = (const float*)d_in[6];
    const float* beps0 = (const float*)d_in[7];
    const float* wmu1 = (const float*)d_in[8];
    const float* wls1 = (const float*)d_in[9];
    const float* bmu1 = (const float*)d_in[10];
    const float* bls1 = (const float*)d_in[11];
    const float* weps1 = (const float*)d_in[12];
    const float* beps1 = (const float*)d_in[13];
    const float* wmuo = (const float*)d_in[14];
    const float* wlso = (const float*)d_in[15];
    const float* bmuo = (const float*)d_in[16];
    const float* blso = (const float*)d_in[17];
    const float* wepso = (const float*)d_in[18];
    const float* bepso = (const float*)d_in[19];
    const float* pfz0 = (const float*)d_in[20];
    const float* pfz1 = (const float*)d_in[21];
    const int* y = (const int*)d_in[22];
    const int* mz0 = (const int*)d_in[23];
    const int* mz1 = (const int*)d_in[24];
    const int* mmu0 = (const int*)d_in[25];
    const int* mmu1 = (const int*)d_in[26];
    const int* dss = (const int*)d_in[27];

    char* ws = (char*)d_ws;
    int* n0p = (int*)(ws + OFF_N0);
    int* n1p = (int*)(ws + OFF_N1);
    float* msum0 = (float*)(ws + OFF_MSUM0);
    float* msum1 = (float*)(ws + OFF_MSUM1);
    int* cpos0 = (int*)(ws + OFF_CPOS0);
    int* cpos1 = (int*)(ws + OFF_CPOS1);
    int* idx0 = (int*)(ws + OFF_IDX0);
    int* idx1 = (int*)(ws + OFF_IDX1);
    double* PXZ = (double*)(ws + OFF_PXZ);
    double* PFL = (double*)(ws + OFF_PFL);
    double* PCE = (double*)(ws + OFF_PCE);
    double* PB = (double*)(ws + OFF_PB);
    double* PW = (double*)(ws + OFF_PW);
    float* bs0 = (float*)(ws + OFF_BS0);
    float* bs1 = (float*)(ws + OFF_BS1);
    float* bso = (float*)(ws + OFF_BSO);
    f16* xh = (f16*)(ws + OFF_XH);
    f16* xl = (f16*)(ws + OFF_XL);
    f16* h0h = (f16*)(ws + OFF_H0H);
    f16* h0l = (f16*)(ws + OFF_H0L);
    f16* h1h = (f16*)(ws + OFF_H1H);
    f16* h1l = (f16*)(ws + OFF_H1L);
    f16* w0ch = (f16*)(ws + OFF_W0CH);
    f16* w0cl = (f16*)(ws + OFF_W0CL);
    f16* w1ch = (f16*)(ws + OFF_W1CH);
    f16* w1cl = (f16*)(ws + OFF_W1CL);
    f16* woch = (f16*)(ws + OFF_WOCH);
    f16* wocl = (f16*)(ws + OFF_WOCL);
    float* part = (float*)(ws + OFF_PART);
    float* out = (float*)d_out;

    idxbuild_kernel<<<1, 1024, 0, stream>>>(mmu0, mmu1, cpos0, idx0, n0p, cpos1, idx1, n1p);
    splitx_kernel<<<1024, 256, 0, stream>>>((const float4*)x, (const float4*)zw,
                                            (f16x4*)xh, (f16x4*)xl, PXZ);
    flowmsum_kernel<<<B_SZ, 256, 0, stream>>>(mz0, pfz0, mmu0, msum0, PFL);
    flowmsum_kernel<<<B_SZ, 256, 0, stream>>>(mz1, pfz1, mmu1, msum1, PFL + 1024);
    bsample_kernel<1><<<16, 256, 0, stream>>>(bmu0, bls0, beps0, bs0, H0_SZ, PB);
    bsample_kernel<1><<<16, 256, 0, stream>>>(bmu1, bls1, beps1, bs1, H1_SZ, PB + 16 * 4);
    bsample_kernel<0><<<4, 256, 0, stream>>>(bmuo, blso, bepso, bso, OUT_SZ, nullptr);

    wsample_rowc_kernel<<<H0_SZ, 256, 0, stream>>>(wmu0, wls0, weps0, mmu0, cpos0,
                                                   w0ch, w0cl, PW);
    wsample_colc_kernel<1, 1><<<H1_SZ, 256, 0, stream>>>(wmu1, wls1, weps1, mmu1, cpos1,
                                                         mmu0, cpos0, n0p, w1ch, w1cl,
                                                         PW + (size_t)4096 * 4);
    wsample_colc_kernel<0, 0><<<OUT_SZ, 256, 0, stream>>>(wmuo, wlso, wepso, nullptr, nullptr,
                                                          mmu1, cpos1, n1p, woch, wocl, nullptr);

    mgemm64<0><<<dim3(64, 16), 256, 0, stream>>>(
        xh, xl, IN_SZ, w0ch, w0cl, IN_SZ, n0p, 0, nullptr, IN_SZ,
        bs0, idx0, mz0, msum0, h0h, h0l, 4096, nullptr);
    mgemm64<0><<<dim3(64, 16), 256, 0, stream>>>(
        h0h, h0l, 4096, w1ch, w1cl, 4096, n1p, 0, n0p, 0,
        bs1, idx1, mz1, msum1, h1h, h1l, 4096, nullptr);
    mgemm64<1><<<dim3(16, 16, 2), 256, 0, stream>>>(
        h1h, h1l, 4096, woch, wocl, 4096, nullptr, OUT_SZ, n1p, 0,
        nullptr, nullptr, nullptr, nullptr, nullptr, nullptr, 0, part);

    ce_fused2_kernel<<<B_SZ, 256, 0, stream>>>(part, bso, y, out, PCE);
    finalize_kernel<<<1, 256, 0, stream>>>(PXZ, PFL, PCE, PB, PW, dss, out);
}